// Round 10
// baseline (38.912 us; speedup 1.0000x reference)
//
#include <hip/hip_runtime.h>

typedef __attribute__((ext_vector_type(8))) short bf16x8;
typedef __attribute__((ext_vector_type(4))) float f32x4;

#define EMB_DIM 400
#define OUT_CH  6
#define ARITY   3
#define BATCH   8192
#define W_OUT   200
#define FC_LEN  1200
#define NT      25      // 16-wide col tiles (400/16)
#define NKS     7       // k-steps of 32 (K=200 padded to 224)
#define BM      32      // batch rows per block
#define NTASK   (ARITY * BM * 100)   // 9600 float4 gather tasks per block
#define NLD     19                   // ceil(NTASK / 512)

static __device__ __forceinline__ ushort f2bf(float f) {
    union { float f; uint u; } v; v.f = f;
    uint u = v.u;
    return (ushort)((u + 0x7FFF + ((u >> 16) & 1)) >> 16);   // RNE
}

// Mb layout: for (i*NT+t, kk): 64 lanes x 8 bf16; lane l, elem j holds
//   B[w = kk*32 + (l>>4)*8 + j][d = t*16 + (l&15)]  (w>=200 -> 0)
// grid (75, 7): x = i*25+t, y = kk (one 32-wide w-slice per block)
__global__ __launch_bounds__(256)
void pack_M(const float* __restrict__ fc2_W, const float* __restrict__ fc2_b,
            const float* __restrict__ fc_W, ushort* __restrict__ Mb) {
    __shared__ float Bt[32][16];
    const int bid = blockIdx.x;            // i*25 + t
    const int kk  = blockIdx.y;
    const int i = bid / NT, t = bid % NT;
    float kc[OUT_CH];
#pragma unroll
    for (int c = 0; c < OUT_CH; ++c) kc[c] = fc2_W[c * 4 + i] + fc2_b[c];
    const int tid = threadIdx.x;
    const int dd = tid >> 4, wl = tid & 15;
    const int d = t * 16 + dd;
#pragma unroll
    for (int s = 0; s < 2; ++s) {
        int w = kk * 32 + wl + 16 * s;
        float v = 0.f;
        if (w < W_OUT) {
#pragma unroll
            for (int c = 0; c < OUT_CH; ++c)
                v = fmaf(kc[c], fc_W[d * FC_LEN + c * W_OUT + w], v);
        }
        Bt[wl + 16 * s][dd] = v;
    }
    __syncthreads();
    if (tid < 64) {
        const int l = tid;
        ushort vals[8];
#pragma unroll
        for (int j = 0; j < 8; ++j)
            vals[j] = f2bf(Bt[(l >> 4) * 8 + j][l & 15]);
        *reinterpret_cast<uint4*>(Mb + ((size_t)(bid * NKS + kk) * 64 + l) * 8) =
            *reinterpret_cast<const uint4*>(vals);
    }
}

__global__ __launch_bounds__(512)
void hype_mfma(const int* __restrict__ r_idx, const int* __restrict__ E_mat,
               const float* __restrict__ ms, const float* __restrict__ bs,
               const float* __restrict__ E_emb, const float* __restrict__ R_emb,
               const float* __restrict__ fc_b, const ushort* __restrict__ Mb,
               float* __restrict__ out) {
    // es: A-fragments. chunk (i, rg, kk) = 64 lanes * 16B, lane-linear.
    __shared__ ushort es[ARITY * 2 * NKS * 64 * 8];   // 43008 B
    __shared__ f32x4  exch[2][4][2][ARITY][64];       // 49152 B (parity dbuf)
    __shared__ float sm_ms[BM * 3], sm_bs[BM * 3], sm_fcb[EMB_DIM];
    __shared__ int   sm_rb[BM], sm_ent[BM * 3];
    __shared__ float osum[4][BM];

    const int tid = threadIdx.x;
    const int b0 = blockIdx.x * BM;

    if (tid < BM * 3) {
        sm_ms[tid]  = ms[b0 * 3 + tid];
        sm_bs[tid]  = bs[b0 * 3 + tid];
        sm_ent[tid] = E_mat[b0 * 3 + tid];
    }
    if (tid >= 96 && tid < 96 + BM) sm_rb[tid - 96] = r_idx[b0 + tid - 96] * EMB_DIM;
    for (int z = tid; z < EMB_DIM; z += 512) sm_fcb[z] = fc_b[z];

    uint* esu = reinterpret_cast<uint*>(es);
    // zero the K-pad: kk=6, lane>=16 regions: 6 pairs * 192 uints
    for (int z = tid; z < ARITY * 2 * 192; z += 512) {
        int pair = z / 192, off = z % 192;
        esu[(pair * NKS + 6) * 256 + 64 + off] = 0;
    }
    __syncthreads();   // sm_ent ready

    // ---- batched gather: issue ALL 19 random loads before any conversion ----
    float4 vreg[NLD];
#pragma unroll
    for (int k = 0; k < NLD; ++k) {
        int tq = tid + k * 512;
        if (tq < NTASK) {
            int q = tq % 100;
            int p = tq / 100;
            int i = p / BM, r = p % BM;
            int ent = sm_ent[r * 3 + i];
            vreg[k] = *reinterpret_cast<const float4*>(
                E_emb + (size_t)ent * EMB_DIM + 4 * q);
        }
    }
#pragma unroll
    for (int k = 0; k < NLD; ++k) {
        int tq = tid + k * 512;
        if (tq < NTASK) {
            int q = tq % 100;
            int p = tq / 100;
            int i = p / BM, r = p % BM;
            int w = 2 * q;                    // covers w, w+1 (same 8-block)
            int kk = w >> 5;
            int lsub = (w >> 3) & 3;
            int j = w & 7;                    // even
            int rg = r >> 4, rl = r & 15;
            int l = lsub * 16 + rl;
            uint pk = (uint)f2bf(vreg[k].x) | ((uint)f2bf(vreg[k].z) << 16);
            esu[(((i * 2 + rg) * NKS + kk) * 64 + l) * 4 + (j >> 1)] = pk;
        }
    }
    __syncthreads();

    const int wid  = tid >> 6;
    const int lane = tid & 63;
    const int kg   = wid & 1;                  // k-half: 0 -> kk 0..3, 1 -> kk 4..6
    const int cg   = wid >> 1;                 // col-group (t-stripe)
    const int cl   = lane & 15;                // col within tile
    const int rql  = lane >> 4;                // row quad
    const int kb   = kg * 4;                   // kk base for this wave

    // A fragments for BOTH row groups, but only this wave's kk-half.
    // Own = my epilogue rows (rg = kg); Oth = partner's rows (rg = 1-kg).
    bf16x8 aOwn[ARITY][4] = {}, aOth[ARITY][4] = {};
#pragma unroll
    for (int i = 0; i < ARITY; ++i)
#pragma unroll
        for (int kkh = 0; kkh < 4; ++kkh)
            if (kkh < 3 || kg == 0) {
                aOwn[i][kkh] = *reinterpret_cast<const bf16x8*>(
                    es + (((i * 2 + kg) * NKS + kb + kkh) * 64 + lane) * 8);
                aOth[i][kkh] = *reinterpret_cast<const bf16x8*>(
                    es + (((i * 2 + (1 - kg)) * NKS + kb + kkh) * 64 + lane) * 8);
            }

    // register-cache epilogue scalars for my 16 rows
    float msv[ARITY][4], bsv[ARITY][4];
    int rbv[4];
#pragma unroll
    for (int r_ = 0; r_ < 4; ++r_) {
        int row = kg * 16 + rql * 4 + r_;
#pragma unroll
        for (int i = 0; i < ARITY; ++i) {
            msv[i][r_] = sm_ms[row * 3 + i];
            bsv[i][r_] = sm_bs[row * 3 + i];
        }
        rbv[r_] = sm_rb[row];
    }

    float rowsum[4] = {0.f, 0.f, 0.f, 0.f};
#pragma unroll 1
    for (int step = 0; step < 7; ++step) {
        const int t = cg + 4 * step;
        f32x4 own[ARITY], oth[ARITY];
#pragma unroll
        for (int i = 0; i < ARITY; ++i) {
            own[i] = (f32x4){0.f, 0.f, 0.f, 0.f};
            oth[i] = (f32x4){0.f, 0.f, 0.f, 0.f};
        }
        if (t < NT) {
#pragma unroll
            for (int i = 0; i < ARITY; ++i) {
                const ushort* bp = Mb + (size_t)(i * NT + t) * NKS * 512
                                      + kb * 512 + lane * 8;
#pragma unroll
                for (int kkh = 0; kkh < 4; ++kkh)
                    if (kkh < 3 || kg == 0) {
                        bf16x8 bfr = *reinterpret_cast<const bf16x8*>(bp + kkh * 512);
                        own[i] = __builtin_amdgcn_mfma_f32_16x16x32_bf16(
                            aOwn[i][kkh], bfr, own[i], 0, 0, 0);
                        oth[i] = __builtin_amdgcn_mfma_f32_16x16x32_bf16(
                            aOth[i][kkh], bfr, oth[i], 0, 0, 0);
                    }
            }
            // publish partner's partial
#pragma unroll
            for (int i = 0; i < ARITY; ++i)
                exch[step & 1][cg][kg][i][lane] = oth[i];
        }
        __syncthreads();
        if (t < NT) {
            f32x4 a0 = own[0] + exch[step & 1][cg][1 - kg][0][lane];
            f32x4 a1 = own[1] + exch[step & 1][cg][1 - kg][1][lane];
            f32x4 a2 = own[2] + exch[step & 1][cg][1 - kg][2][lane];
            const int d = t * 16 + cl;
            const float fcb = sm_fcb[d];
#pragma unroll
            for (int r_ = 0; r_ < 4; ++r_) {
                float Rr = R_emb[rbv[r_] + d];
                float e0 = fmaf(a0[r_] + fcb, msv[0][r_], bsv[0][r_]);
                float e1 = fmaf(a1[r_] + fcb, msv[1][r_], bsv[1][r_]);
                float e2 = fmaf(a2[r_] + fcb, msv[2][r_], bsv[2][r_]);
                rowsum[r_] = fmaf(e0 * e1 * e2, Rr, rowsum[r_]);
            }
        }
    }

#pragma unroll
    for (int m = 1; m < 16; m <<= 1)
#pragma unroll
        for (int r_ = 0; r_ < 4; ++r_)
            rowsum[r_] += __shfl_xor(rowsum[r_], m, 64);
    if (cl == 0) {
#pragma unroll
        for (int r_ = 0; r_ < 4; ++r_)
            osum[cg][kg * 16 + rql * 4 + r_] = rowsum[r_];
    }
    __syncthreads();
    if (tid < BM)
        out[b0 + tid] = osum[0][tid] + osum[1][tid] + osum[2][tid] + osum[3][tid];
}

extern "C" void kernel_launch(void* const* d_in, const int* in_sizes, int n_in,
                              void* d_out, int out_size, void* d_ws, size_t ws_size,
                              hipStream_t stream) {
    const int*   r_idx = (const int*)d_in[0];
    const int*   E_mat = (const int*)d_in[1];
    const float* ms    = (const float*)d_in[2];
    const float* bs    = (const float*)d_in[3];
    const float* E_emb = (const float*)d_in[4];
    const float* R_emb = (const float*)d_in[5];
    const float* fc2_W = (const float*)d_in[6];
    const float* fc2_b = (const float*)d_in[7];
    const float* fc_W  = (const float*)d_in[8];
    const float* fc_b  = (const float*)d_in[9];
    float*  out = (float*)d_out;
    ushort* Mb  = (ushort*)d_ws;     // 3*25*7*64*8*2 = 537600 B

    pack_M<<<dim3(ARITY * NT, NKS), 256, 0, stream>>>(fc2_W, fc2_b, fc_W, Mb);
    hype_mfma<<<BATCH / BM, 512, 0, stream>>>(r_idx, E_mat, ms, bs, E_emb, R_emb,
                                              fc_b, Mb, out);
}

// Round 11
// 30.022 us; speedup vs baseline: 1.2961x; 1.2961x over previous
//
#include <hip/hip_runtime.h>

typedef __attribute__((ext_vector_type(8))) short bf16x8;
typedef __attribute__((ext_vector_type(4))) float f32x4;

#define EMB_DIM 400
#define OUT_CH  6
#define ARITY   3
#define BATCH   8192
#define W_OUT   200
#define FC_LEN  1200
#define NT      25      // 16-wide col tiles (400/16)
#define NKS     7       // k-steps of 32 (K=200 padded to 224)
#define BM      32      // batch rows per block
#define NTH     768     // threads per block (12 waves, 3/SIMD)
#define NWV     12
#define NCG     6       // col-groups (t-stripes)
#define NTASK   (ARITY * BM * 100)   // 9600 float4 gather tasks per block
#define NLD     13                   // ceil(NTASK / NTH)

static __device__ __forceinline__ ushort f2bf(float f) {
    union { float f; uint u; } v; v.f = f;
    uint u = v.u;
    return (ushort)((u + 0x7FFF + ((u >> 16) & 1)) >> 16);   // RNE
}

// Mb layout: for (i*NT+t, kk): 64 lanes x 8 bf16; lane l, elem j holds
//   B[w = kk*32 + (l>>4)*8 + j][d = t*16 + (l&15)]  (w>=200 -> 0)
// grid (75, 7): x = i*25+t, y = kk (one 32-wide w-slice per block)
__global__ __launch_bounds__(256)
void pack_M(const float* __restrict__ fc2_W, const float* __restrict__ fc2_b,
            const float* __restrict__ fc_W, ushort* __restrict__ Mb) {
    __shared__ float Bt[32][16];
    const int bid = blockIdx.x;            // i*25 + t
    const int kk  = blockIdx.y;
    const int i = bid / NT, t = bid % NT;
    float kc[OUT_CH];
#pragma unroll
    for (int c = 0; c < OUT_CH; ++c) kc[c] = fc2_W[c * 4 + i] + fc2_b[c];
    const int tid = threadIdx.x;
    const int dd = tid >> 4, wl = tid & 15;
    const int d = t * 16 + dd;
#pragma unroll
    for (int s = 0; s < 2; ++s) {
        int w = kk * 32 + wl + 16 * s;
        float v = 0.f;
        if (w < W_OUT) {
#pragma unroll
            for (int c = 0; c < OUT_CH; ++c)
                v = fmaf(kc[c], fc_W[d * FC_LEN + c * W_OUT + w], v);
        }
        Bt[wl + 16 * s][dd] = v;
    }
    __syncthreads();
    if (tid < 64) {
        const int l = tid;
        ushort vals[8];
#pragma unroll
        for (int j = 0; j < 8; ++j)
            vals[j] = f2bf(Bt[(l >> 4) * 8 + j][l & 15]);
        *reinterpret_cast<uint4*>(Mb + ((size_t)(bid * NKS + kk) * 64 + l) * 8) =
            *reinterpret_cast<const uint4*>(vals);
    }
}

__global__ __launch_bounds__(NTH)
void hype_mfma(const int* __restrict__ r_idx, const int* __restrict__ E_mat,
               const float* __restrict__ ms, const float* __restrict__ bs,
               const float* __restrict__ E_emb, const float* __restrict__ R_emb,
               const float* __restrict__ fc_b, const ushort* __restrict__ Mb,
               float* __restrict__ out) {
    // es: A-fragments. chunk (i, rg, kk) = 64 lanes * 16B, lane-linear.
    __shared__ ushort es[ARITY * 2 * NKS * 64 * 8];   // 43008 B
    __shared__ float sm_ms[BM * 3], sm_bs[BM * 3], sm_fcb[EMB_DIM];
    __shared__ int   sm_rb[BM], sm_ent[BM * 3];
    __shared__ float osum[NCG][BM];

    const int tid = threadIdx.x;
    const int b0 = blockIdx.x * BM;

    if (tid < BM * 3) {
        sm_ms[tid]  = ms[b0 * 3 + tid];
        sm_bs[tid]  = bs[b0 * 3 + tid];
        sm_ent[tid] = E_mat[b0 * 3 + tid];
    }
    if (tid >= 96 && tid < 96 + BM) sm_rb[tid - 96] = r_idx[b0 + tid - 96] * EMB_DIM;
    for (int z = tid; z < EMB_DIM; z += NTH) sm_fcb[z] = fc_b[z];

    uint* esu = reinterpret_cast<uint*>(es);
    // zero the K-pad: kk=6, lane>=16 regions: 6 pairs * 192 uints
    for (int z = tid; z < ARITY * 2 * 192; z += NTH) {
        int pair = z / 192, off = z % 192;
        esu[(pair * NKS + 6) * 256 + 64 + off] = 0;
    }
    __syncthreads();   // sm_ent ready

    // ---- batched gather: issue ALL 13 random loads before any conversion ----
    float4 vreg[NLD];
#pragma unroll
    for (int k = 0; k < NLD; ++k) {
        int tq = tid + k * NTH;
        if (tq < NTASK) {
            int q = tq % 100;
            int p = tq / 100;
            int i = p / BM, r = p % BM;
            int ent = sm_ent[r * 3 + i];
            vreg[k] = *reinterpret_cast<const float4*>(
                E_emb + (size_t)ent * EMB_DIM + 4 * q);
        }
    }
#pragma unroll
    for (int k = 0; k < NLD; ++k) {
        int tq = tid + k * NTH;
        if (tq < NTASK) {
            int q = tq % 100;
            int p = tq / 100;
            int i = p / BM, r = p % BM;
            int w = 2 * q;                    // covers w, w+1 (same 8-block)
            int kk = w >> 5;
            int lsub = (w >> 3) & 3;
            int j = w & 7;                    // even
            int rg = r >> 4, rl = r & 15;
            int l = lsub * 16 + rl;
            uint pk = (uint)f2bf(vreg[k].x) | ((uint)f2bf(vreg[k].z) << 16);
            esu[(((i * 2 + rg) * NKS + kk) * 64 + l) * 4 + (j >> 1)] = pk;
        }
    }
    __syncthreads();

    const int wid = tid >> 6;
    const int lane = tid & 63;
    const int rg = wid & 1, cg = wid >> 1;     // rg: row-group, cg: col-group 0..5
    const int cl = lane & 15;                   // col within tile
    const int rql = lane >> 4;                  // row quad

    // preload all A fragments for this wave's 16 rows (3 i * 7 kk = 84 VGPR)
    bf16x8 afrag[ARITY][NKS];
#pragma unroll
    for (int i = 0; i < ARITY; ++i)
#pragma unroll
        for (int kk = 0; kk < NKS; ++kk)
            afrag[i][kk] = *reinterpret_cast<const bf16x8*>(
                es + (((i * 2 + rg) * NKS + kk) * 64 + lane) * 8);

    float msv[ARITY][4], bsv[ARITY][4];
    int rbv[4];
#pragma unroll
    for (int r_ = 0; r_ < 4; ++r_) {
        int row = rg * 16 + rql * 4 + r_;
#pragma unroll
        for (int i = 0; i < ARITY; ++i) {
            msv[i][r_] = sm_ms[row * 3 + i];
            bsv[i][r_] = sm_bs[row * 3 + i];
        }
        rbv[r_] = sm_rb[row];
    }

    float rowsum[4] = {0.f, 0.f, 0.f, 0.f};
    for (int t = cg; t < NT; t += NCG) {
        f32x4 acc[ARITY];
#pragma unroll
        for (int i = 0; i < ARITY; ++i) {
            f32x4 a = {0.f, 0.f, 0.f, 0.f};
            const ushort* bp = Mb + ((size_t)(i * NT + t) * NKS * 64 + lane) * 8;
#pragma unroll
            for (int kk = 0; kk < NKS; ++kk) {
                bf16x8 bfr = *reinterpret_cast<const bf16x8*>(bp + kk * 512);
                a = __builtin_amdgcn_mfma_f32_16x16x32_bf16(afrag[i][kk], bfr, a, 0, 0, 0);
            }
            acc[i] = a;
        }
        const int d = t * 16 + cl;
        const float fcb = sm_fcb[d];
#pragma unroll
        for (int r_ = 0; r_ < 4; ++r_) {
            float Rr = R_emb[rbv[r_] + d];
            float e0 = fmaf(acc[0][r_] + fcb, msv[0][r_], bsv[0][r_]);
            float e1 = fmaf(acc[1][r_] + fcb, msv[1][r_], bsv[1][r_]);
            float e2 = fmaf(acc[2][r_] + fcb, msv[2][r_], bsv[2][r_]);
            rowsum[r_] = fmaf(e0 * e1 * e2, Rr, rowsum[r_]);
        }
    }

#pragma unroll
    for (int m = 1; m < 16; m <<= 1)
#pragma unroll
        for (int r_ = 0; r_ < 4; ++r_)
            rowsum[r_] += __shfl_xor(rowsum[r_], m, 64);
    if (cl == 0) {
#pragma unroll
        for (int r_ = 0; r_ < 4; ++r_)
            osum[cg][rg * 16 + rql * 4 + r_] = rowsum[r_];
    }
    __syncthreads();
    if (tid < BM) {
        float s = 0.f;
#pragma unroll
        for (int w = 0; w < NCG; ++w) s += osum[w][tid];
        out[b0 + tid] = s;
    }
}

extern "C" void kernel_launch(void* const* d_in, const int* in_sizes, int n_in,
                              void* d_out, int out_size, void* d_ws, size_t ws_size,
                              hipStream_t stream) {
    const int*   r_idx = (const int*)d_in[0];
    const int*   E_mat = (const int*)d_in[1];
    const float* ms    = (const float*)d_in[2];
    const float* bs    = (const float*)d_in[3];
    const float* E_emb = (const float*)d_in[4];
    const float* R_emb = (const float*)d_in[5];
    const float* fc2_W = (const float*)d_in[6];
    const float* fc2_b = (const float*)d_in[7];
    const float* fc_W  = (const float*)d_in[8];
    const float* fc_b  = (const float*)d_in[9];
    float*  out = (float*)d_out;
    ushort* Mb  = (ushort*)d_ws;     // 3*25*7*64*8*2 = 537600 B

    pack_M<<<dim3(ARITY * NT, NKS), 256, 0, stream>>>(fc2_W, fc2_b, fc_W, Mb);
    hype_mfma<<<BATCH / BM, NTH, 0, stream>>>(r_idx, E_mat, ms, bs, E_emb, R_emb,
                                              fc_b, Mb, out);
}